// Round 2
// baseline (656.018 us; speedup 1.0000x reference)
//
#include <hip/hip_runtime.h>
#include <hip/hip_bf16.h>

#define NN 4096
#define HD 128
#define KG 4
#define NC 10
#define CAP 64

// ---------------- prep: permuted/transposed LSTM weights ----------------
// Wp[dir][j][h*4+g] = (j<128 ? wih[g*128+h][j] : whh[g*128+h][j-128])
// bp[dir][h*4+g]    = bih[g*128+h] + bhh[g*128+h]
__global__ __launch_bounds__(256) void prep_kernel(
    const float* __restrict__ wih_f, const float* __restrict__ whh_f,
    const float* __restrict__ bih_f, const float* __restrict__ bhh_f,
    const float* __restrict__ wih_b, const float* __restrict__ whh_b,
    const float* __restrict__ bih_b, const float* __restrict__ bhh_b,
    float* __restrict__ Wp, float* __restrict__ bp)
{
    int tid = blockIdx.x * 256 + threadIdx.x;
    if (tid < 2 * 256 * 512) {
        int dir = tid >> 17;
        int rem = tid & ((1 << 17) - 1);
        int j   = rem >> 9;
        int col = rem & 511;
        int h = col >> 2, g = col & 3;
        const float* wih = dir ? wih_b : wih_f;
        const float* whh = dir ? whh_b : whh_f;
        float v = (j < HD) ? wih[(g * HD + h) * HD + j]
                           : whh[(g * HD + h) * HD + (j - HD)];
        Wp[tid] = v;
    }
    if (tid < 2 * 512) {
        int dir = tid >> 9;
        int col = tid & 511;
        int h = col >> 2, g = col & 3;
        const float* bih = dir ? bih_b : bih_f;
        const float* bhh = dir ? bhh_b : bhh_f;
        bp[tid] = bih[g * HD + h] + bhh[g * HD + h];
    }
}

// ---------------- extract: adjacency -> edge lists + dinv ----------------
// adj layout [N][N][K]; one block per source row i, coalesced float4 reads.
__global__ __launch_bounds__(256) void extract_kernel(
    const float* __restrict__ adj, float* __restrict__ dinv,
    int* __restrict__ ecnt, unsigned short* __restrict__ edges)
{
    int i = blockIdx.x;
    __shared__ int cnt[KG];
    if (threadIdx.x < KG) cnt[threadIdx.x] = 0;
    __syncthreads();
    const float4* row = (const float4*)(adj + (size_t)i * NN * KG);
    for (int j = threadIdx.x; j < NN; j += 256) {
        float4 v = row[j];
        if (v.x != 0.f) { int p = atomicAdd(&cnt[0], 1); if (p < CAP) edges[((size_t)(0 * NN + i)) * CAP + p] = (unsigned short)j; }
        if (v.y != 0.f) { int p = atomicAdd(&cnt[1], 1); if (p < CAP) edges[((size_t)(1 * NN + i)) * CAP + p] = (unsigned short)j; }
        if (v.z != 0.f) { int p = atomicAdd(&cnt[2], 1); if (p < CAP) edges[((size_t)(2 * NN + i)) * CAP + p] = (unsigned short)j; }
        if (v.w != 0.f) { int p = atomicAdd(&cnt[3], 1); if (p < CAP) edges[((size_t)(3 * NN + i)) * CAP + p] = (unsigned short)j; }
    }
    __syncthreads();
    if (threadIdx.x < KG) {
        int c = cnt[threadIdx.x];
        ecnt[threadIdx.x * NN + i] = c > CAP ? CAP : c;
        dinv[threadIdx.x * NN + i] = rsqrtf((float)c + 1.0f);  // A_hat = A + I
    }
}

// ---------------- fp32 GEMM core: 128x128 tile, 8x8/thread, K chunks of 32 ----
// As transposed [kk][r] for float4 a-reads; Bs [kk][c].
template <int NPARTS>
__device__ inline void gemm_core(const float* A1, const float* A2,
                                 const float* __restrict__ B, int ldb,
                                 int m0, int bn0, float acc[8][8], float* lds)
{
    float* As = lds;              // 32*128
    float* Bs = lds + 32 * 128;   // 32*128
    int tid = threadIdx.x;
    int tx = tid & 15, ty = tid >> 4;
#pragma unroll
    for (int part = 0; part < NPARTS; ++part) {
        const float* A = (part == 0) ? A1 : A2;
        for (int kc = 0; kc < HD; kc += 32) {
#pragma unroll
            for (int it = 0; it < 4; ++it) {
                int f = tid + it * 256;             // 0..1023
                int r = f >> 3, q = f & 7;          // A: 128 rows x 8 float4
                float4 va = *(const float4*)(A + (size_t)(m0 + r) * HD + kc + (q << 2));
                As[(q * 4 + 0) * 128 + r] = va.x;
                As[(q * 4 + 1) * 128 + r] = va.y;
                As[(q * 4 + 2) * 128 + r] = va.z;
                As[(q * 4 + 3) * 128 + r] = va.w;
                int rb = f >> 5, cb = (f & 31) << 2; // B: 32 rows x 32 float4
                *(float4*)(Bs + rb * 128 + cb) =
                    *(const float4*)(B + (size_t)(part * HD + kc + rb) * ldb + bn0 + cb);
            }
            __syncthreads();
#pragma unroll
            for (int kk = 0; kk < 32; ++kk) {
                float4 a0 = *(const float4*)(As + kk * 128 + ty * 8);
                float4 a1 = *(const float4*)(As + kk * 128 + ty * 8 + 4);
                float4 b0 = *(const float4*)(Bs + kk * 128 + tx * 8);
                float4 b1 = *(const float4*)(Bs + kk * 128 + tx * 8 + 4);
                float av[8] = {a0.x, a0.y, a0.z, a0.w, a1.x, a1.y, a1.z, a1.w};
                float bv[8] = {b0.x, b0.y, b0.z, b0.w, b1.x, b1.y, b1.z, b1.w};
#pragma unroll
                for (int i = 0; i < 8; ++i)
#pragma unroll
                    for (int j = 0; j < 8; ++j)
                        acc[i][j] = fmaf(av[i], bv[j], acc[i][j]);
            }
            __syncthreads();
        }
    }
}

// ---------------- GCN feature GEMM: C[k] = A(or A[k]) @ W[k] ----------------
__global__ __launch_bounds__(256) void gemm_gcn_kernel(
    const float* __restrict__ Aall, int a_per_k,
    const float* __restrict__ W, float* __restrict__ C)
{
    __shared__ float lds[2 * 32 * 128];
    int k = blockIdx.z;
    int m0 = blockIdx.y * 128;
    const float* A1 = Aall + (a_per_k ? (size_t)k * NN * HD : 0);
    float acc[8][8] = {};
    gemm_core<1>(A1, nullptr, W + (size_t)k * HD * HD, HD, m0, 0, acc, lds);
    int tx = threadIdx.x & 15, ty = threadIdx.x >> 4;
    float* Cb = C + (size_t)k * NN * HD;
#pragma unroll
    for (int i = 0; i < 8; ++i) {
        int r = m0 + ty * 8 + i;
        *(float4*)(Cb + (size_t)r * HD + tx * 8)     = *(float4*)&acc[i][0];
        *(float4*)(Cb + (size_t)r * HD + tx * 8 + 4) = *(float4*)&acc[i][4];
    }
}

// ---------------- SpMM: Out[k][i] = dinv_i*(sum_j dinv_j*Z[k][j] + dinv_i*Z[k][i]) + b[k]
__global__ __launch_bounds__(256) void spmm_kernel(
    const float* __restrict__ Z, const float* __restrict__ dinv,
    const int* __restrict__ ecnt, const unsigned short* __restrict__ edges,
    const float* __restrict__ bias, float* __restrict__ Out)
{
    int wid = threadIdx.x >> 6;
    int lane = threadIdx.x & 63;
    int idx = blockIdx.x * 4 + wid;   // idx = k*NN + i
    int k = idx >> 12;
    int i = idx & (NN - 1);
    int cnt = ecnt[idx];
    float di = dinv[idx];
    const unsigned short* el = edges + (size_t)idx * CAP;
    const float* Zk = Z + (size_t)k * NN * HD;
    int h2 = lane * 2;
    float ax = 0.f, ay = 0.f;
    for (int e = 0; e < cnt; ++e) {
        int j = el[e];
        float dj = dinv[(k << 12) + j];
        float2 z = *(const float2*)(Zk + (size_t)j * HD + h2);
        ax = fmaf(dj, z.x, ax);
        ay = fmaf(dj, z.y, ay);
    }
    float2 zi = *(const float2*)(Zk + (size_t)i * HD + h2);
    ax = fmaf(di, zi.x, ax);
    ay = fmaf(di, zi.y, ay);
    float2 b = *(const float2*)(bias + k * HD + h2);
    float2 o;
    o.x = fmaf(di, ax, b.x);
    o.y = fmaf(di, ay, b.y);
    *(float2*)(Out + (size_t)idx * HD + h2) = o;
}

// ---------------- LSTM step: gates GEMM + fused pointwise epilogue ----------
// hs[2][KG][NN][HD]; cstate[2][NN][HD]. A2 (h_prev) read from hs of previous step.
template <int FIRST>
__global__ __launch_bounds__(256) void lstm_step_kernel(
    const float* __restrict__ gnn, float* __restrict__ hs,
    float* __restrict__ cstate, const float* __restrict__ Wp,
    const float* __restrict__ bp, int t)
{
    __shared__ float lds[2 * 32 * 128];
    int dir = blockIdx.z;
    int kin   = (dir == 0) ? t : (KG - 1 - t);        // input element this step
    int kprev = (dir == 0) ? (t - 1) : (KG - t);      // where prev h lives
    int m0 = blockIdx.y * 128;
    int bn0 = blockIdx.x * 128;
    const float* A1 = gnn + (size_t)kin * NN * HD;
    const float* B = Wp + (size_t)dir * 256 * 512;
    float acc[8][8] = {};
    if (FIRST) {
        gemm_core<1>(A1, nullptr, B, 512, m0, bn0, acc, lds);
    } else {
        const float* A2 = hs + ((size_t)dir * KG + kprev) * NN * HD;
        gemm_core<2>(A1, A2, B, 512, m0, bn0, acc, lds);
    }
    int tx = threadIdx.x & 15, ty = threadIdx.x >> 4;
    const float* bpd = bp + dir * 512;
    float* hout = hs + ((size_t)dir * KG + kin) * NN * HD;
    float* cst = cstate + (size_t)dir * NN * HD;
    int c0 = bn0 + tx * 8;  // permuted cols: h = c0/4 (+1), gates 0..3 = i,f,g,o
    float bv[8];
#pragma unroll
    for (int j = 0; j < 8; ++j) bv[j] = bpd[c0 + j];
#pragma unroll
    for (int i = 0; i < 8; ++i) {
        int n = m0 + ty * 8 + i;
#pragma unroll
        for (int hh = 0; hh < 2; ++hh) {
            int h = (c0 >> 2) + hh;
            float gi = acc[i][hh * 4 + 0] + bv[hh * 4 + 0];
            float gf = acc[i][hh * 4 + 1] + bv[hh * 4 + 1];
            float gg = acc[i][hh * 4 + 2] + bv[hh * 4 + 2];
            float go = acc[i][hh * 4 + 3] + bv[hh * 4 + 3];
            float cold = FIRST ? 0.f : cst[(size_t)n * HD + h];
            float si = 1.f / (1.f + __expf(-gi));
            float sf = 1.f / (1.f + __expf(-gf));
            float so = 1.f / (1.f + __expf(-go));
            float e2g = __expf(2.f * gg);
            float tg = 1.f - 2.f / (e2g + 1.f);       // tanh, inf-safe
            float cn = fmaf(sf, cold, si * tg);
            float e2c = __expf(2.f * cn);
            float tc = 1.f - 2.f / (e2c + 1.f);
            cst[(size_t)n * HD + h] = cn;
            hout[(size_t)n * HD + h] = so * tc;
        }
    }
}

// ---------------- finalize: attn logits -> softmax -> pool -> classify ------
__global__ __launch_bounds__(256) void finalize_kernel(
    const float* __restrict__ gnn, const float* __restrict__ hs,
    const float* __restrict__ rw, const float* __restrict__ ow,
    const float* __restrict__ ob, float* __restrict__ out)
{
    int wid = threadIdx.x >> 6, lane = threadIdx.x & 63;
    int n = blockIdx.x * 4 + wid;
    float w0 = rw[lane], w1 = rw[lane + 64];
    float w2 = rw[128 + lane], w3 = rw[192 + lane];
    float lg[KG];
#pragma unroll
    for (int k = 0; k < KG; ++k) {
        const float* hf = hs + ((size_t)k * NN + n) * HD;
        const float* hb = hs + ((size_t)(KG + k) * NN + n) * HD;
        lg[k] = hf[lane] * w0 + hf[lane + 64] * w1 + hb[lane] * w2 + hb[lane + 64] * w3;
    }
#pragma unroll
    for (int s = 32; s > 0; s >>= 1)
#pragma unroll
        for (int k = 0; k < KG; ++k) lg[k] += __shfl_xor(lg[k], s);
    float mx = lg[0];
#pragma unroll
    for (int k = 1; k < KG; ++k) mx = fmaxf(mx, lg[k]);
    float es[KG], se = 0.f;
#pragma unroll
    for (int k = 0; k < KG; ++k) { es[k] = __expf(lg[k] - mx); se += es[k]; }
    float inv = 1.f / se;
    float p0 = 0.f, p1 = 0.f;
#pragma unroll
    for (int k = 0; k < KG; ++k) {
        float a = es[k] * inv;
        p0 = fmaf(a, gnn[((size_t)k * NN + n) * HD + lane], p0);
        p1 = fmaf(a, gnn[((size_t)k * NN + n) * HD + lane + 64], p1);
    }
    float oc[NC];
#pragma unroll
    for (int c = 0; c < NC; ++c)
        oc[c] = p0 * ow[c * HD + lane] + p1 * ow[c * HD + lane + 64];
#pragma unroll
    for (int s = 32; s > 0; s >>= 1)
#pragma unroll
        for (int c = 0; c < NC; ++c) oc[c] += __shfl_xor(oc[c], s);
    float omx = oc[0] + ob[0];
#pragma unroll
    for (int c = 0; c < NC; ++c) { oc[c] += ob[c]; omx = fmaxf(omx, oc[c]); }
    float osum = 0.f;
#pragma unroll
    for (int c = 0; c < NC; ++c) { oc[c] = __expf(oc[c] - omx); osum += oc[c]; }
    float oinv = 1.f / osum;
    if (lane < NC) out[(size_t)n * NC + lane] = oc[lane] * oinv;
}

extern "C" void kernel_launch(void* const* d_in, const int* in_sizes, int n_in,
                              void* d_out, int out_size, void* d_ws, size_t ws_size,
                              hipStream_t stream)
{
    const float* feat  = (const float*)d_in[0];
    const float* adj   = (const float*)d_in[1];
    const float* gw1   = (const float*)d_in[2];
    const float* gb1   = (const float*)d_in[3];
    const float* gw2   = (const float*)d_in[4];
    const float* gb2   = (const float*)d_in[5];
    const float* wih_f = (const float*)d_in[6];
    const float* whh_f = (const float*)d_in[7];
    const float* bih_f = (const float*)d_in[8];
    const float* bhh_f = (const float*)d_in[9];
    const float* wih_b = (const float*)d_in[10];
    const float* whh_b = (const float*)d_in[11];
    const float* bih_b = (const float*)d_in[12];
    const float* bhh_b = (const float*)d_in[13];
    const float* rw    = (const float*)d_in[14];
    const float* ow    = (const float*)d_in[16];
    const float* ob    = (const float*)d_in[17];
    float* out = (float*)d_out;

    char* ws = (char*)d_ws;
    float*          dinv  = (float*)(ws);                    // 64 KB
    int*            ecnt  = (int*)(ws + 65536);              // 64 KB
    unsigned short* edges = (unsigned short*)(ws + 131072);  // 2 MB
    float*          Z     = (float*)(ws + 2228224);          // 8 MB
    float*          G     = (float*)(ws + 10616832);         // 8 MB
    float*          hsb   = (float*)(ws + 19005440);         // 16 MB
    float*          cst   = (float*)(ws + 35782656);         // 4 MB
    float*          Wp    = (float*)(ws + 39976960);         // 1 MB
    float*          bp    = (float*)(ws + 41025536);         // 4 KB

    prep_kernel<<<1024, 256, 0, stream>>>(wih_f, whh_f, bih_f, bhh_f,
                                          wih_b, whh_b, bih_b, bhh_b, Wp, bp);
    extract_kernel<<<NN, 256, 0, stream>>>(adj, dinv, ecnt, edges);
    gemm_gcn_kernel<<<dim3(1, 32, KG), 256, 0, stream>>>(feat, 0, gw1, Z);
    spmm_kernel<<<KG * NN / 4, 256, 0, stream>>>(Z, dinv, ecnt, edges, gb1, G);
    gemm_gcn_kernel<<<dim3(1, 32, KG), 256, 0, stream>>>(G, 1, gw2, Z);
    spmm_kernel<<<KG * NN / 4, 256, 0, stream>>>(Z, dinv, ecnt, edges, gb2, G);
    lstm_step_kernel<1><<<dim3(4, 32, 2), 256, 0, stream>>>(G, hsb, cst, Wp, bp, 0);
    for (int t = 1; t < KG; ++t)
        lstm_step_kernel<0><<<dim3(4, 32, 2), 256, 0, stream>>>(G, hsb, cst, Wp, bp, t);
    finalize_kernel<<<NN / 4, 256, 0, stream>>>(G, hsb, rw, ow, ob, out);
}

// Round 3
// 548.291 us; speedup vs baseline: 1.1965x; 1.1965x over previous
//
#include <hip/hip_runtime.h>
#include <hip/hip_bf16.h>

#define NN 4096
#define HD 128
#define KG 4
#define NC 10
#define CAP 64

typedef __attribute__((ext_vector_type(8))) short bf16x8;
typedef __attribute__((ext_vector_type(4))) float f32x4;

__device__ inline unsigned short f2b(float x) {   // fp32 -> bf16 RNE
    unsigned u = __float_as_uint(x);
    return (unsigned short)((u + 0x7FFFu + ((u >> 16) & 1u)) >> 16);
}
__device__ inline uint2 pack4(float4 v) {
    uint2 p;
    p.x = (unsigned)f2b(v.x) | ((unsigned)f2b(v.y) << 16);
    p.y = (unsigned)f2b(v.z) | ((unsigned)f2b(v.w) << 16);
    return p;
}

// ---------------- prep: bf16 [n][k] weight transposes ----------------
// Wp [2][512][256]: n = tn*128 + wn*64 + g*16 + c -> h = tn*32+wn*16+c, gate g
// bp [2][512] fp32 same ordering.
// Wg1p/Wg2p [512][128]: n = kg*128 + hcol, k = feature dim.
__global__ __launch_bounds__(256) void prep_kernel(
    const float* __restrict__ wih_f, const float* __restrict__ whh_f,
    const float* __restrict__ bih_f, const float* __restrict__ bhh_f,
    const float* __restrict__ wih_b, const float* __restrict__ whh_b,
    const float* __restrict__ bih_b, const float* __restrict__ bhh_b,
    const float* __restrict__ gw1, const float* __restrict__ gw2,
    unsigned short* __restrict__ Wp, float* __restrict__ bp,
    unsigned short* __restrict__ Wg1p, unsigned short* __restrict__ Wg2p)
{
    int tid = blockIdx.x * 256 + threadIdx.x;
    if (tid < 2 * 512 * 256) {
        int dir = tid >> 17;
        int rem = tid & 131071;
        int n = rem >> 8, k = rem & 255;
        int tn = n >> 7, wn = (n >> 6) & 1, g = (n >> 4) & 3, c = n & 15;
        int h = tn * 32 + wn * 16 + c;
        int row = g * HD + h;
        const float* wih = dir ? wih_b : wih_f;
        const float* whh = dir ? whh_b : whh_f;
        float v = (k < HD) ? wih[row * HD + k] : whh[row * HD + (k - HD)];
        Wp[tid] = f2b(v);
    } else if (tid < 2 * 512 * 256 + 512 * 128) {
        int t = tid - 2 * 512 * 256;
        int n = t >> 7, k = t & 127;
        int kg = n >> 7, hcol = n & 127;
        Wg1p[t] = f2b(gw1[((size_t)kg * HD + k) * HD + hcol]);
    } else if (tid < 2 * 512 * 256 + 2 * 512 * 128) {
        int t = tid - (2 * 512 * 256 + 512 * 128);
        int n = t >> 7, k = t & 127;
        int kg = n >> 7, hcol = n & 127;
        Wg2p[t] = f2b(gw2[((size_t)kg * HD + k) * HD + hcol]);
    }
    if (tid < 2 * 512) {
        int dir = tid >> 9, n = tid & 511;
        int tn = n >> 7, wn = (n >> 6) & 1, g = (n >> 4) & 3, c = n & 15;
        int h = tn * 32 + wn * 16 + c;
        int row = g * HD + h;
        const float* bih = dir ? bih_b : bih_f;
        const float* bhh = dir ? bhh_b : bhh_f;
        bp[tid] = bih[row] + bhh[row];
    }
}

// ---------------- extract: adjacency -> edge lists + dinv ----------------
__global__ __launch_bounds__(256) void extract_kernel(
    const float* __restrict__ adj, float* __restrict__ dinv,
    int* __restrict__ ecnt, unsigned short* __restrict__ edges)
{
    int i = blockIdx.x;
    __shared__ int cnt[KG];
    if (threadIdx.x < KG) cnt[threadIdx.x] = 0;
    __syncthreads();
    const float4* row = (const float4*)(adj + (size_t)i * NN * KG);
    for (int j = threadIdx.x; j < NN; j += 256) {
        float4 v = row[j];
        if (v.x != 0.f) { int p = atomicAdd(&cnt[0], 1); if (p < CAP) edges[((size_t)(0 * NN + i)) * CAP + p] = (unsigned short)j; }
        if (v.y != 0.f) { int p = atomicAdd(&cnt[1], 1); if (p < CAP) edges[((size_t)(1 * NN + i)) * CAP + p] = (unsigned short)j; }
        if (v.z != 0.f) { int p = atomicAdd(&cnt[2], 1); if (p < CAP) edges[((size_t)(2 * NN + i)) * CAP + p] = (unsigned short)j; }
        if (v.w != 0.f) { int p = atomicAdd(&cnt[3], 1); if (p < CAP) edges[((size_t)(3 * NN + i)) * CAP + p] = (unsigned short)j; }
    }
    __syncthreads();
    if (threadIdx.x < KG) {
        int c = cnt[threadIdx.x];
        ecnt[threadIdx.x * NN + i] = c > CAP ? CAP : c;
        dinv[threadIdx.x * NN + i] = rsqrtf((float)c + 1.0f);
    }
}

// ---------------- MFMA GEMM building blocks ----------------
// LDS tiles: A [64 rows][32 k] bf16, row stride 40 ushorts (80 B, 2-way bank max)
//            B [128 rows(n)][32 k] bf16, stride 40.
__device__ inline void stageA(const float* __restrict__ A, int lda, int m0, int kc,
                              unsigned short* Abuf)
{
    int t = threadIdx.x;
#pragma unroll
    for (int it = 0; it < 2; ++it) {
        int f = t + it * 256;            // 0..511
        int r = f >> 3, q = f & 7;       // 64 rows x 8 float4
        float4 v = *(const float4*)(A + (size_t)(m0 + r) * lda + kc + (q << 2));
        *(uint2*)&Abuf[r * 40 + q * 4] = pack4(v);
    }
}
__device__ inline void stageB(const unsigned short* __restrict__ Bp, int ldk,
                              int bn0, int kc, unsigned short* Bbuf)
{
    int t = threadIdx.x;
#pragma unroll
    for (int it = 0; it < 2; ++it) {
        int f = t + it * 256;            // 0..511
        int r = f >> 2, q = f & 3;       // 128 rows x 4 (8-bf16 quads)
        uint4 v = *(const uint4*)(Bp + (size_t)(bn0 + r) * ldk + kc + (q << 3));
        *(uint4*)&Bbuf[r * 40 + q * 8] = v;
    }
}
__device__ inline void mfma_chunk(const unsigned short* Abuf, const unsigned short* Bbuf,
                                  int wm, int wn, int lane, f32x4 acc[2][4])
{
    int la = lane & 15, kb = (lane >> 4) * 8;
    bf16x8 a[2], b[4];
#pragma unroll
    for (int m = 0; m < 2; ++m)
        a[m] = *(const bf16x8*)&Abuf[(wm * 32 + m * 16 + la) * 40 + kb];
#pragma unroll
    for (int n = 0; n < 4; ++n)
        b[n] = *(const bf16x8*)&Bbuf[(wn * 64 + n * 16 + la) * 40 + kb];
#pragma unroll
    for (int m = 0; m < 2; ++m)
#pragma unroll
        for (int n = 0; n < 4; ++n)
            acc[m][n] = __builtin_amdgcn_mfma_f32_16x16x32_bf16(a[m], b[n], acc[m][n], 0, 0, 0);
}

// ---------------- GCN GEMM: Z[kg] = A(kg) @ W[kg], K=128, tile 64x128 ----------
__global__ __launch_bounds__(256) void gemm_gcn_mfma(
    const float* __restrict__ Aall, int a_per_k,
    const unsigned short* __restrict__ Bp, float* __restrict__ C)
{
    __shared__ unsigned short Abuf[64 * 40];
    __shared__ unsigned short Bbuf[128 * 40];
    int kg = blockIdx.x;
    int m0 = blockIdx.y * 64;
    const float* A = Aall + (a_per_k ? (size_t)kg * NN * HD : 0);
    int wid = threadIdx.x >> 6, lane = threadIdx.x & 63;
    int wm = wid >> 1, wn = wid & 1;
    f32x4 acc[2][4] = {};
    for (int ch = 0; ch < 4; ++ch) {
        stageA(A, HD, m0, ch * 32, Abuf);
        stageB(Bp, HD, kg * 128, ch * 32, Bbuf);
        __syncthreads();
        mfma_chunk(Abuf, Bbuf, wm, wn, lane, acc);
        __syncthreads();
    }
    float* Cb = C + (size_t)kg * NN * HD;
    int la = lane & 15, lj = lane >> 4;
#pragma unroll
    for (int m = 0; m < 2; ++m)
#pragma unroll
        for (int n = 0; n < 4; ++n)
#pragma unroll
            for (int j = 0; j < 4; ++j) {
                int r = m0 + wm * 32 + m * 16 + lj * 4 + j;
                int col = wn * 64 + n * 16 + la;
                Cb[(size_t)r * HD + col] = acc[m][n][j];
            }
}

// ---------------- SpMM (unchanged) ----------------
__global__ __launch_bounds__(256) void spmm_kernel(
    const float* __restrict__ Z, const float* __restrict__ dinv,
    const int* __restrict__ ecnt, const unsigned short* __restrict__ edges,
    const float* __restrict__ bias, float* __restrict__ Out)
{
    int wid = threadIdx.x >> 6;
    int lane = threadIdx.x & 63;
    int idx = blockIdx.x * 4 + wid;   // idx = k*NN + i
    int k = idx >> 12;
    int i = idx & (NN - 1);
    int cnt = ecnt[idx];
    float di = dinv[idx];
    const unsigned short* el = edges + (size_t)idx * CAP;
    const float* Zk = Z + (size_t)k * NN * HD;
    int h2 = lane * 2;
    float ax = 0.f, ay = 0.f;
    for (int e = 0; e < cnt; ++e) {
        int j = el[e];
        float dj = dinv[(k << 12) + j];
        float2 z = *(const float2*)(Zk + (size_t)j * HD + h2);
        ax = fmaf(dj, z.x, ax);
        ay = fmaf(dj, z.y, ay);
    }
    float2 zi = *(const float2*)(Zk + (size_t)i * HD + h2);
    ax = fmaf(di, zi.x, ax);
    ay = fmaf(di, zi.y, ay);
    float2 b = *(const float2*)(bias + k * HD + h2);
    float2 o;
    o.x = fmaf(di, ax, b.x);
    o.y = fmaf(di, ay, b.y);
    *(float2*)(Out + (size_t)idx * HD + h2) = o;
}

// ---------------- LSTM step: MFMA gates GEMM + fused cell update -------------
// K = 256 (x | h_prev). Lane's 4 N-frags = gates i,f,g,o of ONE hidden unit.
template <int FIRST>
__global__ __launch_bounds__(256) void lstm_step_mfma(
    const float* __restrict__ gnn, float* __restrict__ hs,
    float* __restrict__ cstate, const unsigned short* __restrict__ Wp,
    const float* __restrict__ bp, int t)
{
    __shared__ unsigned short Abuf[64 * 40];
    __shared__ unsigned short Bbuf[128 * 40];
    int dir = blockIdx.z;
    int kin   = (dir == 0) ? t : (KG - 1 - t);
    int kprev = (dir == 0) ? (t - 1) : (KG - t);
    int bn0 = blockIdx.x * 128;          // tile_n = blockIdx.x
    int m0  = blockIdx.y * 64;
    int wid = threadIdx.x >> 6, lane = threadIdx.x & 63;
    int wm = wid >> 1, wn = wid & 1;
    const unsigned short* B = Wp + (size_t)dir * 512 * 256;
    const float* A1 = gnn + (size_t)kin * NN * HD;
    const float* A2 = FIRST ? A1 : hs + ((size_t)dir * KG + kprev) * NN * HD;
    f32x4 acc[2][4] = {};
    int nch = FIRST ? 4 : 8;
    for (int ch = 0; ch < nch; ++ch) {
        const float* A = (ch < 4) ? A1 : A2;
        stageA(A, HD, m0, (ch & 3) * 32, Abuf);
        stageB(B, 256, bn0, ch * 32, Bbuf);
        __syncthreads();
        mfma_chunk(Abuf, Bbuf, wm, wn, lane, acc);
        __syncthreads();
    }
    int la = lane & 15, lj = lane >> 4;
    int h = blockIdx.x * 32 + wn * 16 + la;      // this lane's hidden unit
    const float* bpd = bp + dir * 512;
    float bi = bpd[bn0 + wn * 64 + 0 * 16 + la];
    float bf = bpd[bn0 + wn * 64 + 1 * 16 + la];
    float bg = bpd[bn0 + wn * 64 + 2 * 16 + la];
    float bo = bpd[bn0 + wn * 64 + 3 * 16 + la];
    float* hout = hs + ((size_t)dir * KG + kin) * NN * HD;
    float* cst = cstate + (size_t)dir * NN * HD;
#pragma unroll
    for (int m = 0; m < 2; ++m)
#pragma unroll
        for (int j = 0; j < 4; ++j) {
            int n = m0 + wm * 32 + m * 16 + lj * 4 + j;
            float gi = acc[m][0][j] + bi;
            float gf = acc[m][1][j] + bf;
            float gg = acc[m][2][j] + bg;
            float go = acc[m][3][j] + bo;
            float cold = FIRST ? 0.f : cst[(size_t)n * HD + h];
            float si = 1.f / (1.f + __expf(-gi));
            float sf = 1.f / (1.f + __expf(-gf));
            float so = 1.f / (1.f + __expf(-go));
            float e2g = __expf(2.f * gg);
            float tg = 1.f - 2.f / (e2g + 1.f);
            float cn = fmaf(sf, cold, si * tg);
            float e2c = __expf(2.f * cn);
            float tc = 1.f - 2.f / (e2c + 1.f);
            cst[(size_t)n * HD + h] = cn;
            hout[(size_t)n * HD + h] = so * tc;
        }
}

// ---------------- finalize (unchanged) ----------------
__global__ __launch_bounds__(256) void finalize_kernel(
    const float* __restrict__ gnn, const float* __restrict__ hs,
    const float* __restrict__ rw, const float* __restrict__ ow,
    const float* __restrict__ ob, float* __restrict__ out)
{
    int wid = threadIdx.x >> 6, lane = threadIdx.x & 63;
    int n = blockIdx.x * 4 + wid;
    float w0 = rw[lane], w1 = rw[lane + 64];
    float w2 = rw[128 + lane], w3 = rw[192 + lane];
    float lg[KG];
#pragma unroll
    for (int k = 0; k < KG; ++k) {
        const float* hf = hs + ((size_t)k * NN + n) * HD;
        const float* hb = hs + ((size_t)(KG + k) * NN + n) * HD;
        lg[k] = hf[lane] * w0 + hf[lane + 64] * w1 + hb[lane] * w2 + hb[lane + 64] * w3;
    }
#pragma unroll
    for (int s = 32; s > 0; s >>= 1)
#pragma unroll
        for (int k = 0; k < KG; ++k) lg[k] += __shfl_xor(lg[k], s);
    float mx = lg[0];
#pragma unroll
    for (int k = 1; k < KG; ++k) mx = fmaxf(mx, lg[k]);
    float es[KG], se = 0.f;
#pragma unroll
    for (int k = 0; k < KG; ++k) { es[k] = __expf(lg[k] - mx); se += es[k]; }
    float inv = 1.f / se;
    float p0 = 0.f, p1 = 0.f;
#pragma unroll
    for (int k = 0; k < KG; ++k) {
        float a = es[k] * inv;
        p0 = fmaf(a, gnn[((size_t)k * NN + n) * HD + lane], p0);
        p1 = fmaf(a, gnn[((size_t)k * NN + n) * HD + lane + 64], p1);
    }
    float oc[NC];
#pragma unroll
    for (int c = 0; c < NC; ++c)
        oc[c] = p0 * ow[c * HD + lane] + p1 * ow[c * HD + lane + 64];
#pragma unroll
    for (int s = 32; s > 0; s >>= 1)
#pragma unroll
        for (int c = 0; c < NC; ++c) oc[c] += __shfl_xor(oc[c], s);
    float omx = oc[0] + ob[0];
#pragma unroll
    for (int c = 0; c < NC; ++c) { oc[c] += ob[c]; omx = fmaxf(omx, oc[c]); }
    float osum = 0.f;
#pragma unroll
    for (int c = 0; c < NC; ++c) { oc[c] = __expf(oc[c] - omx); osum += oc[c]; }
    float oinv = 1.f / osum;
    if (lane < NC) out[(size_t)n * NC + lane] = oc[lane] * oinv;
}

extern "C" void kernel_launch(void* const* d_in, const int* in_sizes, int n_in,
                              void* d_out, int out_size, void* d_ws, size_t ws_size,
                              hipStream_t stream)
{
    const float* feat  = (const float*)d_in[0];
    const float* adj   = (const float*)d_in[1];
    const float* gw1   = (const float*)d_in[2];
    const float* gb1   = (const float*)d_in[3];
    const float* gw2   = (const float*)d_in[4];
    const float* gb2   = (const float*)d_in[5];
    const float* wih_f = (const float*)d_in[6];
    const float* whh_f = (const float*)d_in[7];
    const float* bih_f = (const float*)d_in[8];
    const float* bhh_f = (const float*)d_in[9];
    const float* wih_b = (const float*)d_in[10];
    const float* whh_b = (const float*)d_in[11];
    const float* bih_b = (const float*)d_in[12];
    const float* bhh_b = (const float*)d_in[13];
    const float* rw    = (const float*)d_in[14];
    const float* ow    = (const float*)d_in[16];
    const float* ob    = (const float*)d_in[17];
    float* out = (float*)d_out;

    char* ws = (char*)d_ws;
    float*          dinv  = (float*)(ws);                    // 64 KB
    int*            ecnt  = (int*)(ws + 65536);              // 64 KB
    unsigned short* edges = (unsigned short*)(ws + 131072);  // 2 MB
    float*          Z     = (float*)(ws + 2228224);          // 8 MB
    float*          G     = (float*)(ws + 10616832);         // 8 MB
    float*          hsb   = (float*)(ws + 19005440);         // 16 MB
    float*          cst   = (float*)(ws + 35782656);         // 4 MB
    unsigned short* Wp    = (unsigned short*)(ws + 39976960);// 512 KB
    float*          bp    = (float*)(ws + 40501248);         // 4 KB
    unsigned short* Wg1p  = (unsigned short*)(ws + 40505344);// 128 KB
    unsigned short* Wg2p  = (unsigned short*)(ws + 40636416);// 128 KB

    prep_kernel<<<1536, 256, 0, stream>>>(wih_f, whh_f, bih_f, bhh_f,
                                          wih_b, whh_b, bih_b, bhh_b,
                                          gw1, gw2, Wp, bp, Wg1p, Wg2p);
    extract_kernel<<<NN, 256, 0, stream>>>(adj, dinv, ecnt, edges);
    gemm_gcn_mfma<<<dim3(KG, 64), 256, 0, stream>>>(feat, 0, Wg1p, Z);
    spmm_kernel<<<KG * NN / 4, 256, 0, stream>>>(Z, dinv, ecnt, edges, gb1, G);
    gemm_gcn_mfma<<<dim3(KG, 64), 256, 0, stream>>>(G, 1, Wg2p, Z);
    spmm_kernel<<<KG * NN / 4, 256, 0, stream>>>(Z, dinv, ecnt, edges, gb2, G);
    lstm_step_mfma<1><<<dim3(4, 64, 2), 256, 0, stream>>>(G, hsb, cst, Wp, bp, 0);
    for (int t = 1; t < KG; ++t)
        lstm_step_mfma<0><<<dim3(4, 64, 2), 256, 0, stream>>>(G, hsb, cst, Wp, bp, t);
    finalize_kernel<<<NN / 4, 256, 0, stream>>>(G, hsb, rw, ow, ob, out);
}

// Round 4
// 544.191 us; speedup vs baseline: 1.2055x; 1.0075x over previous
//
#include <hip/hip_runtime.h>
#include <hip/hip_bf16.h>

#define NN 4096
#define HD 128
#define KG 4
#define NC 10
#define CAP 64

typedef __attribute__((ext_vector_type(8))) short bf16x8;
typedef __attribute__((ext_vector_type(4))) float f32x4;

__device__ inline unsigned short f2b(float x) {   // fp32 -> bf16 RNE
    unsigned u = __float_as_uint(x);
    return (unsigned short)((u + 0x7FFFu + ((u >> 16) & 1u)) >> 16);
}
__device__ inline float b2f(unsigned short b) {
    return __uint_as_float((unsigned)b << 16);
}

// ======== setup: extract edges + all weight transposes + feat->bf16 ========
// Wp [2][512][256] bf16: n = (hq*4+g)*16+hr  <->  h = hq*16+hr, gate g (i,f,g,o)
//   k<128: wih col k (input x);  k>=128: whh col k-128 (h_prev, plain unit order)
// bp [2][512] fp32, same n-permutation.
// Wg1p/Wg2p [512][128] bf16: n = kg*128 + hcol.
__global__ __launch_bounds__(256) void setup_kernel(
    const float* __restrict__ adj, const float* __restrict__ feat,
    const float* __restrict__ wih_f, const float* __restrict__ whh_f,
    const float* __restrict__ bih_f, const float* __restrict__ bhh_f,
    const float* __restrict__ wih_b, const float* __restrict__ whh_b,
    const float* __restrict__ bih_b, const float* __restrict__ bhh_b,
    const float* __restrict__ gw1, const float* __restrict__ gw2,
    float* __restrict__ dinv, int* __restrict__ ecnt,
    unsigned short* __restrict__ edges, unsigned* __restrict__ featb,
    unsigned short* __restrict__ Wp, float* __restrict__ bp,
    unsigned short* __restrict__ Wg1p, unsigned short* __restrict__ Wg2p)
{
    int b = blockIdx.x;
    __shared__ int cnt[KG];
    if (b < NN) {
        int i = b;
        if (threadIdx.x < KG) cnt[threadIdx.x] = 0;
        __syncthreads();
        const float4* row = (const float4*)(adj + (size_t)i * NN * KG);
        for (int j = threadIdx.x; j < NN; j += 256) {
            float4 v = row[j];
            if (v.x != 0.f) { int p = atomicAdd(&cnt[0], 1); if (p < CAP) edges[((size_t)(0 * NN + i)) * CAP + p] = (unsigned short)j; }
            if (v.y != 0.f) { int p = atomicAdd(&cnt[1], 1); if (p < CAP) edges[((size_t)(1 * NN + i)) * CAP + p] = (unsigned short)j; }
            if (v.z != 0.f) { int p = atomicAdd(&cnt[2], 1); if (p < CAP) edges[((size_t)(2 * NN + i)) * CAP + p] = (unsigned short)j; }
            if (v.w != 0.f) { int p = atomicAdd(&cnt[3], 1); if (p < CAP) edges[((size_t)(3 * NN + i)) * CAP + p] = (unsigned short)j; }
        }
        __syncthreads();
        if (threadIdx.x < KG) {
            int c = cnt[threadIdx.x];
            ecnt[threadIdx.x * NN + i] = c > CAP ? CAP : c;
            dinv[threadIdx.x * NN + i] = rsqrtf((float)c + 1.0f);
        }
    } else if (b < NN + 1024) {                       // Wp: 262144 elems
        int t = (b - NN) * 256 + threadIdx.x;
        int dir = t >> 17, rem = t & 131071;
        int n = rem >> 8, k = rem & 255;
        int hq = n >> 6, g = (n >> 4) & 3, hr = n & 15;
        int row = g * HD + hq * 16 + hr;
        const float* wih = dir ? wih_b : wih_f;
        const float* whh = dir ? whh_b : whh_f;
        Wp[t] = f2b(k < HD ? wih[row * HD + k] : whh[row * HD + (k - HD)]);
    } else if (b < NN + 1280) {                       // Wg1p: 65536
        int t = (b - NN - 1024) * 256 + threadIdx.x;
        int n = t >> 7, k = t & 127;
        Wg1p[t] = f2b(gw1[(((size_t)(n >> 7)) * HD + k) * HD + (n & 127)]);
    } else if (b < NN + 1536) {                       // Wg2p: 65536
        int t = (b - NN - 1280) * 256 + threadIdx.x;
        int n = t >> 7, k = t & 127;
        Wg2p[t] = f2b(gw2[(((size_t)(n >> 7)) * HD + k) * HD + (n & 127)]);
    } else if (b < NN + 2560) {                       // featb: 262144 uint pairs
        int t = (b - NN - 1536) * 256 + threadIdx.x;
        float2 v = *(const float2*)&feat[2 * (size_t)t];
        featb[t] = (unsigned)f2b(v.x) | ((unsigned)f2b(v.y) << 16);
    } else {                                          // bp: 1024
        int t = (b - NN - 2560) * 256 + threadIdx.x;
        if (t < 1024) {
            int dir = t >> 9, n = t & 511;
            int hq = n >> 6, g = (n >> 4) & 3, hr = n & 15;
            int row = g * HD + hq * 16 + hr;
            bp[t] = dir ? (bih_b[row] + bhh_b[row]) : (bih_f[row] + bhh_f[row]);
        }
    }
}

// ======== GCN GEMM: C[kg] = A(kg) @ W[kg], bf16 A, tile 64x128, K=128 ========
__global__ __launch_bounds__(256) void gemm_gcn_mfma(
    const unsigned short* __restrict__ Ab, int a_per_k,
    const unsigned short* __restrict__ Bp, float* __restrict__ C)
{
    __shared__ unsigned short Abuf[64 * 40];
    __shared__ unsigned short Bbuf[128 * 40];
    int kg = blockIdx.x, m0 = blockIdx.y * 64;
    const unsigned short* A = Ab + (a_per_k ? (size_t)kg * NN * HD : 0);
    int wid = threadIdx.x >> 6, lane = threadIdx.x & 63;
    int wm = wid >> 1, wn = wid & 1;
    int la = lane & 15, kb = (lane >> 4) * 8;
    f32x4 acc[2][4] = {};
    for (int ch = 0; ch < 4; ++ch) {
        {
            int t = threadIdx.x, r = t >> 2, q = t & 3;
            *(uint4*)&Abuf[r * 40 + q * 8] =
                *(const uint4*)&A[((size_t)(m0 + r)) * HD + ch * 32 + q * 8];
        }
#pragma unroll
        for (int it = 0; it < 2; ++it) {
            int f = threadIdx.x + it * 256;
            int r = f >> 2, q = f & 3;
            *(uint4*)&Bbuf[r * 40 + q * 8] =
                *(const uint4*)&Bp[((size_t)(kg * 128 + r)) * HD + ch * 32 + q * 8];
        }
        __syncthreads();
        bf16x8 a[2], bb[4];
#pragma unroll
        for (int m = 0; m < 2; ++m)
            a[m] = *(const bf16x8*)&Abuf[(wm * 32 + m * 16 + la) * 40 + kb];
#pragma unroll
        for (int n = 0; n < 4; ++n)
            bb[n] = *(const bf16x8*)&Bbuf[(wn * 64 + n * 16 + la) * 40 + kb];
#pragma unroll
        for (int m = 0; m < 2; ++m)
#pragma unroll
            for (int n = 0; n < 4; ++n)
                acc[m][n] = __builtin_amdgcn_mfma_f32_16x16x32_bf16(a[m], bb[n], acc[m][n], 0, 0, 0);
        __syncthreads();
    }
    float* Cb = C + (size_t)kg * NN * HD;
    int lj = lane >> 4;
#pragma unroll
    for (int m = 0; m < 2; ++m)
#pragma unroll
        for (int n = 0; n < 4; ++n)
#pragma unroll
            for (int j = 0; j < 4; ++j) {
                int r = m0 + wm * 32 + m * 16 + lj * 4 + j;
                int col = wn * 64 + n * 16 + la;
                Cb[(size_t)r * HD + col] = acc[m][n][j];
            }
}

// ======== SpMM: Out = D^-1/2 (A+I) D^-1/2 Z + b; writes bf16 (+opt fp32) ====
template <int WF32>
__global__ __launch_bounds__(256) void spmm_kernel(
    const float* __restrict__ Z, const float* __restrict__ dinv,
    const int* __restrict__ ecnt, const unsigned short* __restrict__ edges,
    const float* __restrict__ bias, float* __restrict__ Out,
    unsigned* __restrict__ Outb)
{
    int wid = threadIdx.x >> 6;
    int lane = threadIdx.x & 63;
    int idx = blockIdx.x * 4 + wid;   // idx = k*NN + i
    int k = idx >> 12;
    int i = idx & (NN - 1);
    int cnt = ecnt[idx];
    float di = dinv[idx];
    const unsigned short* el = edges + (size_t)idx * CAP;
    const float* Zk = Z + (size_t)k * NN * HD;
    int h2 = lane * 2;
    float ax = 0.f, ay = 0.f;
    for (int e = 0; e < cnt; ++e) {
        int j = el[e];
        float dj = dinv[(k << 12) + j];
        float2 z = *(const float2*)(Zk + (size_t)j * HD + h2);
        ax = fmaf(dj, z.x, ax);
        ay = fmaf(dj, z.y, ay);
    }
    float2 zi = *(const float2*)(Zk + (size_t)i * HD + h2);
    ax = fmaf(di, zi.x, ax);
    ay = fmaf(di, zi.y, ay);
    float2 bv = *(const float2*)(bias + k * HD + h2);
    float2 o;
    o.x = fmaf(di, ax, bv.x);
    o.y = fmaf(di, ay, bv.y);
    if (WF32) *(float2*)(Out + (size_t)idx * HD + h2) = o;
    Outb[(size_t)idx * 64 + lane] = (unsigned)f2b(o.x) | ((unsigned)f2b(o.y) << 16);
}

// ======== fused biLSTM: one kernel, t-loop internal, h in LDS, c in regs ====
// Block = 64 rows x 1 dir, 4 waves; wave wn owns n-slice [wn*128, wn*128+128)
// = units [wn*32, wn*32+32) x gates. K=256: chunks 0-3 x-part (A=G2b),
// chunks 4-7 h-part (A read directly from hlds).
__global__ __launch_bounds__(256) void lstm_fused(
    const unsigned short* __restrict__ G2b, unsigned short* __restrict__ hsb,
    const unsigned short* __restrict__ Wp, const float* __restrict__ bp)
{
    __shared__ unsigned short Bbuf[512 * 40];   // 40 KB
    __shared__ unsigned short Abuf[64 * 40];    // 5 KB
    __shared__ unsigned short hlds[64 * 136];   // 17 KB
    int m0 = blockIdx.x * 64;
    int dir = blockIdx.y;
    int wid = threadIdx.x >> 6, lane = threadIdx.x & 63;
    int la = lane & 15, lj = lane >> 4, kb = lj * 8;
    const unsigned short* B = Wp + (size_t)dir * 512 * 256;
    float c_st[4][2][4] = {};
    float bias[2][4];
#pragma unroll
    for (int ch = 0; ch < 2; ++ch)
#pragma unroll
        for (int g = 0; g < 4; ++g)
            bias[ch][g] = bp[dir * 512 + wid * 128 + (ch * 4 + g) * 16 + la];

    for (int t = 0; t < KG; ++t) {
        int kin = dir ? (KG - 1 - t) : t;
        f32x4 acc[4][8] = {};
        int nch = (t == 0) ? 4 : 8;
        for (int ch = 0; ch < nch; ++ch) {
            if (ch < 4) {   // stage x chunk from G2b
                int r = threadIdx.x >> 2, q = threadIdx.x & 3;
                *(uint4*)&Abuf[r * 40 + q * 8] =
                    *(const uint4*)&G2b[((size_t)kin * NN + m0 + r) * HD + ch * 32 + q * 8];
            }
#pragma unroll
            for (int it = 0; it < 8; ++it) {   // stage B chunk [512][32]
                int f = threadIdx.x + it * 256;
                int r = f >> 2, q = f & 3;
                *(uint4*)&Bbuf[r * 40 + q * 8] =
                    *(const uint4*)&B[(size_t)r * 256 + ch * 32 + q * 8];
            }
            __syncthreads();
            bf16x8 bfr[8];
#pragma unroll
            for (int fi = 0; fi < 8; ++fi)
                bfr[fi] = *(const bf16x8*)&Bbuf[(wid * 128 + fi * 16 + la) * 40 + kb];
#pragma unroll
            for (int m = 0; m < 4; ++m) {
                bf16x8 afr = (ch < 4)
                    ? *(const bf16x8*)&Abuf[(m * 16 + la) * 40 + kb]
                    : *(const bf16x8*)&hlds[(m * 16 + la) * 136 + (ch - 4) * 32 + kb];
#pragma unroll
                for (int fi = 0; fi < 8; ++fi)
                    acc[m][fi] = __builtin_amdgcn_mfma_f32_16x16x32_bf16(afr, bfr[fi], acc[m][fi], 0, 0, 0);
            }
            __syncthreads();
        }
        // epilogue: cell update, h -> hlds (bf16) + global hs
        unsigned short* hout = hsb + ((size_t)(dir * KG + kin) * NN) * HD;
#pragma unroll
        for (int m = 0; m < 4; ++m)
#pragma unroll
            for (int j = 0; j < 4; ++j) {
                int r = m * 16 + lj * 4 + j;
#pragma unroll
                for (int chf = 0; chf < 2; ++chf) {
                    int h = wid * 32 + chf * 16 + la;
                    float gi = acc[m][chf * 4 + 0][j] + bias[chf][0];
                    float gf = acc[m][chf * 4 + 1][j] + bias[chf][1];
                    float gg = acc[m][chf * 4 + 2][j] + bias[chf][2];
                    float go = acc[m][chf * 4 + 3][j] + bias[chf][3];
                    float cold = c_st[m][chf][j];
                    float si = 1.f / (1.f + __expf(-gi));
                    float sf = 1.f / (1.f + __expf(-gf));
                    float so = 1.f / (1.f + __expf(-go));
                    float e2g = __expf(2.f * gg);
                    float tg = 1.f - 2.f / (e2g + 1.f);
                    float cn = fmaf(sf, cold, si * tg);
                    float e2c = __expf(2.f * cn);
                    float tc = 1.f - 2.f / (e2c + 1.f);
                    c_st[m][chf][j] = cn;
                    unsigned short hb = f2b(so * tc);
                    hlds[r * 136 + h] = hb;
                    hout[(size_t)(m0 + r) * HD + h] = hb;
                }
            }
        __syncthreads();   // hlds(t) complete before next step's h-chunks
    }
}

// ======== finalize: attn softmax over k -> pool -> classify ========
__global__ __launch_bounds__(256) void finalize_kernel(
    const float* __restrict__ gnn, const unsigned* __restrict__ hsu,
    const float* __restrict__ rw, const float* __restrict__ ow,
    const float* __restrict__ ob, float* __restrict__ out)
{
    int wid = threadIdx.x >> 6, lane = threadIdx.x & 63;
    int n = blockIdx.x * 4 + wid;
    int u0 = 2 * lane;
    float w0 = rw[u0], w1 = rw[u0 + 1];
    float w2 = rw[HD + u0], w3 = rw[HD + u0 + 1];
    float lg[KG];
#pragma unroll
    for (int k = 0; k < KG; ++k) {
        unsigned hf = hsu[((size_t)k * NN + n) * 64 + lane];
        unsigned hb = hsu[((size_t)(KG + k) * NN + n) * 64 + lane];
        lg[k] = b2f((unsigned short)hf) * w0 + b2f((unsigned short)(hf >> 16)) * w1
              + b2f((unsigned short)hb) * w2 + b2f((unsigned short)(hb >> 16)) * w3;
    }
#pragma unroll
    for (int s = 32; s > 0; s >>= 1)
#pragma unroll
        for (int k = 0; k < KG; ++k) lg[k] += __shfl_xor(lg[k], s);
    float mx = lg[0];
#pragma unroll
    for (int k = 1; k < KG; ++k) mx = fmaxf(mx, lg[k]);
    float es[KG], se = 0.f;
#pragma unroll
    for (int k = 0; k < KG; ++k) { es[k] = __expf(lg[k] - mx); se += es[k]; }
    float inv = 1.f / se;
    float p0 = 0.f, p1 = 0.f;
#pragma unroll
    for (int k = 0; k < KG; ++k) {
        float a = es[k] * inv;
        float2 g = *(const float2*)(gnn + ((size_t)k * NN + n) * HD + u0);
        p0 = fmaf(a, g.x, p0);
        p1 = fmaf(a, g.y, p1);
    }
    float oc[NC];
#pragma unroll
    for (int c = 0; c < NC; ++c)
        oc[c] = p0 * ow[c * HD + u0] + p1 * ow[c * HD + u0 + 1];
#pragma unroll
    for (int s = 32; s > 0; s >>= 1)
#pragma unroll
        for (int c = 0; c < NC; ++c) oc[c] += __shfl_xor(oc[c], s);
    float omx = oc[0] + ob[0];
#pragma unroll
    for (int c = 0; c < NC; ++c) { oc[c] += ob[c]; omx = fmaxf(omx, oc[c]); }
    float osum = 0.f;
#pragma unroll
    for (int c = 0; c < NC; ++c) { oc[c] = __expf(oc[c] - omx); osum += oc[c]; }
    float oinv = 1.f / osum;
    if (lane < NC) out[(size_t)n * NC + lane] = oc[lane] * oinv;
}

extern "C" void kernel_launch(void* const* d_in, const int* in_sizes, int n_in,
                              void* d_out, int out_size, void* d_ws, size_t ws_size,
                              hipStream_t stream)
{
    const float* feat  = (const float*)d_in[0];
    const float* adj   = (const float*)d_in[1];
    const float* gw1   = (const float*)d_in[2];
    const float* gb1   = (const float*)d_in[3];
    const float* gw2   = (const float*)d_in[4];
    const float* gb2   = (const float*)d_in[5];
    const float* wih_f = (const float*)d_in[6];
    const float* whh_f = (const float*)d_in[7];
    const float* bih_f = (const float*)d_in[8];
    const float* bhh_f = (const float*)d_in[9];
    const float* wih_b = (const float*)d_in[10];
    const float* whh_b = (const float*)d_in[11];
    const float* bih_b = (const float*)d_in[12];
    const float* bhh_b = (const float*)d_in[13];
    const float* rw    = (const float*)d_in[14];
    const float* ow    = (const float*)d_in[16];
    const float* ob    = (const float*)d_in[17];
    float* out = (float*)d_out;

    char* ws = (char*)d_ws;
    float*          dinv  = (float*)(ws);                      // 64 KB
    int*            ecnt  = (int*)(ws + 65536);                // 64 KB
    unsigned short* edges = (unsigned short*)(ws + 131072);    // 2 MB   -> 2228224
    unsigned*       featb = (unsigned*)(ws + 2228224);         // 1 MB   -> 3276800
    float*          Z     = (float*)(ws + 3276800);            // 8 MB   -> 11665408
    unsigned*       G1b   = (unsigned*)(ws + 11665408);        // 4 MB   -> 15859712
    float*          G2    = (float*)(ws + 15859712);           // 8 MB   -> 24248320
    unsigned*       G2b   = (unsigned*)(ws + 24248320);        // 4 MB   -> 28442624
    unsigned short* hsb   = (unsigned short*)(ws + 28442624);  // 8 MB   -> 36831232
    unsigned short* Wp    = (unsigned short*)(ws + 36831232);  // 512 KB -> 37355520
    float*          bp    = (float*)(ws + 37355520);           // 4 KB   -> 37359616
    unsigned short* Wg1p  = (unsigned short*)(ws + 37359616);  // 128 KB -> 37490688
    unsigned short* Wg2p  = (unsigned short*)(ws + 37490688);  // 128 KB

    setup_kernel<<<NN + 2564, 256, 0, stream>>>(
        adj, feat, wih_f, whh_f, bih_f, bhh_f, wih_b, whh_b, bih_b, bhh_b,
        gw1, gw2, dinv, ecnt, edges, featb, Wp, bp, Wg1p, Wg2p);
    gemm_gcn_mfma<<<dim3(KG, 64), 256, 0, stream>>>((const unsigned short*)featb, 0, Wg1p, Z);
    spmm_kernel<0><<<KG * NN / 4, 256, 0, stream>>>(Z, dinv, ecnt, edges, gb1, nullptr, G1b);
    gemm_gcn_mfma<<<dim3(KG, 64), 256, 0, stream>>>((const unsigned short*)G1b, 1, Wg2p, Z);
    spmm_kernel<1><<<KG * NN / 4, 256, 0, stream>>>(Z, dinv, ecnt, edges, gb2, G2, G2b);
    lstm_fused<<<dim3(64, 2), 256, 0, stream>>>((const unsigned short*)G2b, hsb, Wp, bp);
    finalize_kernel<<<NN / 4, 256, 0, stream>>>(G2, (const unsigned*)hsb, rw, ow, ob, out);
}

// Round 5
// 499.334 us; speedup vs baseline: 1.3138x; 1.0898x over previous
//
#include <hip/hip_runtime.h>
#include <hip/hip_bf16.h>

#define NN 4096
#define HD 128
#define KG 4
#define NC 10
#define CAP 64

typedef __attribute__((ext_vector_type(8))) short bf16x8;
typedef __attribute__((ext_vector_type(4))) float f32x4;

__device__ inline unsigned short f2b(float x) {   // fp32 -> bf16 RNE
    unsigned u = __float_as_uint(x);
    return (unsigned short)((u + 0x7FFFu + ((u >> 16) & 1u)) >> 16);
}
__device__ inline float b2f(unsigned short b) {
    return __uint_as_float((unsigned)b << 16);
}

// ======== setup: extract (ballot compaction) + weight transposes + feat->bf16 ====
// Wp [2][512][256] bf16: n = (hq*4+g)*16+hr <-> h=hq*16+hr, gate g (i,f,g,o)
// bp [2][512] fp32 same perm.  Wg1p/Wg2p [512][128] bf16: n = kg*128+hcol.
__global__ __launch_bounds__(256) void setup_kernel(
    const float* __restrict__ adj, const float* __restrict__ feat,
    const float* __restrict__ wih_f, const float* __restrict__ whh_f,
    const float* __restrict__ bih_f, const float* __restrict__ bhh_f,
    const float* __restrict__ wih_b, const float* __restrict__ whh_b,
    const float* __restrict__ bih_b, const float* __restrict__ bhh_b,
    const float* __restrict__ gw1, const float* __restrict__ gw2,
    float* __restrict__ dinv, int* __restrict__ ecnt,
    unsigned short* __restrict__ edges, unsigned* __restrict__ featb,
    unsigned short* __restrict__ Wp, float* __restrict__ bp,
    unsigned short* __restrict__ Wg1p, unsigned short* __restrict__ Wg2p)
{
    int b = blockIdx.x;
    __shared__ int cnt[KG];
    if (b < NN) {
        int i = b;
        int lane = threadIdx.x & 63;
        if (threadIdx.x < KG) cnt[threadIdx.x] = 0;
        __syncthreads();
        const float4* row = (const float4*)(adj + (size_t)i * NN * KG);
        unsigned long long below = (1ull << lane) - 1ull;
        for (int j = threadIdx.x; j < NN; j += 256) {
            float4 v = row[j];
#pragma unroll
            for (int k = 0; k < KG; ++k) {
                float comp = (k == 0) ? v.x : (k == 1) ? v.y : (k == 2) ? v.z : v.w;
                unsigned long long mask = __ballot(comp != 0.f);
                if (mask) {                       // wave-uniform
                    int base;
                    if (lane == 0) base = atomicAdd(&cnt[k], __popcll(mask));
                    base = __shfl(base, 0);
                    if (comp != 0.f) {
                        int p = base + (int)__popcll(mask & below);
                        if (p < CAP)
                            edges[((size_t)(k * NN + i)) * CAP + p] = (unsigned short)j;
                    }
                }
            }
        }
        __syncthreads();
        if (threadIdx.x < KG) {
            int c = cnt[threadIdx.x];
            ecnt[threadIdx.x * NN + i] = c > CAP ? CAP : c;
            dinv[threadIdx.x * NN + i] = rsqrtf((float)c + 1.0f);
        }
    } else if (b < NN + 1024) {                       // Wp: 262144 elems
        int t = (b - NN) * 256 + threadIdx.x;
        int dir = t >> 17, rem = t & 131071;
        int n = rem >> 8, k = rem & 255;
        int hq = n >> 6, g = (n >> 4) & 3, hr = n & 15;
        int row = g * HD + hq * 16 + hr;
        const float* wih = dir ? wih_b : wih_f;
        const float* whh = dir ? whh_b : whh_f;
        Wp[t] = f2b(k < HD ? wih[row * HD + k] : whh[row * HD + (k - HD)]);
    } else if (b < NN + 1280) {                       // Wg1p: 65536
        int t = (b - NN - 1024) * 256 + threadIdx.x;
        int n = t >> 7, k = t & 127;
        Wg1p[t] = f2b(gw1[(((size_t)(n >> 7)) * HD + k) * HD + (n & 127)]);
    } else if (b < NN + 1536) {                       // Wg2p: 65536
        int t = (b - NN - 1280) * 256 + threadIdx.x;
        int n = t >> 7, k = t & 127;
        Wg2p[t] = f2b(gw2[(((size_t)(n >> 7)) * HD + k) * HD + (n & 127)]);
    } else if (b < NN + 2560) {                       // featb: 262144 uint pairs
        int t = (b - NN - 1536) * 256 + threadIdx.x;
        float2 v = *(const float2*)&feat[2 * (size_t)t];
        featb[t] = (unsigned)f2b(v.x) | ((unsigned)f2b(v.y) << 16);
    } else {                                          // bp: 1024
        int t = (b - NN - 2560) * 256 + threadIdx.x;
        if (t < 1024) {
            int dir = t >> 9, n = t & 511;
            int hq = n >> 6, g = (n >> 4) & 3, hr = n & 15;
            int row = g * HD + hq * 16 + hr;
            bp[t] = dir ? (bih_b[row] + bhh_b[row]) : (bih_f[row] + bhh_f[row]);
        }
    }
}

// ======== GCN GEMM: Zs[kg] = dinv ⊙ (A(kg) @ W[kg]), bf16 out, tile 64x128 ====
__global__ __launch_bounds__(256) void gemm_gcn_mfma(
    const unsigned short* __restrict__ Ab, int a_per_k,
    const unsigned short* __restrict__ Bp, const float* __restrict__ dinv,
    unsigned short* __restrict__ Cb)
{
    __shared__ unsigned short Abuf[64 * 40];
    __shared__ unsigned short Bbuf[128 * 40];
    int kg = blockIdx.x, m0 = blockIdx.y * 64;
    const unsigned short* A = Ab + (a_per_k ? (size_t)kg * NN * HD : 0);
    int wid = threadIdx.x >> 6, lane = threadIdx.x & 63;
    int wm = wid >> 1, wn = wid & 1;
    int la = lane & 15, kb = (lane >> 4) * 8;
    f32x4 acc[2][4] = {};
    for (int ch = 0; ch < 4; ++ch) {
        {
            int t = threadIdx.x, r = t >> 2, q = t & 3;
            *(uint4*)&Abuf[r * 40 + q * 8] =
                *(const uint4*)&A[((size_t)(m0 + r)) * HD + ch * 32 + q * 8];
        }
#pragma unroll
        for (int it = 0; it < 2; ++it) {
            int f = threadIdx.x + it * 256;
            int r = f >> 2, q = f & 3;
            *(uint4*)&Bbuf[r * 40 + q * 8] =
                *(const uint4*)&Bp[((size_t)(kg * 128 + r)) * HD + ch * 32 + q * 8];
        }
        __syncthreads();
        bf16x8 a[2], bb[4];
#pragma unroll
        for (int m = 0; m < 2; ++m)
            a[m] = *(const bf16x8*)&Abuf[(wm * 32 + m * 16 + la) * 40 + kb];
#pragma unroll
        for (int n = 0; n < 4; ++n)
            bb[n] = *(const bf16x8*)&Bbuf[(wn * 64 + n * 16 + la) * 40 + kb];
#pragma unroll
        for (int m = 0; m < 2; ++m)
#pragma unroll
            for (int n = 0; n < 4; ++n)
                acc[m][n] = __builtin_amdgcn_mfma_f32_16x16x32_bf16(a[m], bb[n], acc[m][n], 0, 0, 0);
        __syncthreads();
    }
    unsigned short* Ck = Cb + (size_t)kg * NN * HD;
    const float* dv = dinv + kg * NN;
    int lj = lane >> 4;
#pragma unroll
    for (int m = 0; m < 2; ++m)
#pragma unroll
        for (int j = 0; j < 4; ++j) {
            int r = m0 + wm * 32 + m * 16 + lj * 4 + j;
            float d = dv[r];
#pragma unroll
            for (int n = 0; n < 4; ++n) {
                int col = wn * 64 + n * 16 + la;
                Ck[(size_t)r * HD + col] = f2b(acc[m][n][j] * d);
            }
        }
}

// ======== SpMM: Out_i = di*(Σ_j Zs[j] + Zs[i]) + b   (Zs pre-scaled bf16) ====
// Wave per row; edge list in registers, shfl-broadcast, 4 gathers in flight.
__global__ __launch_bounds__(256) void spmm_kernel(
    const unsigned* __restrict__ Zs, const float* __restrict__ dinv,
    const int* __restrict__ ecnt, const unsigned short* __restrict__ edges,
    const float* __restrict__ bias, unsigned* __restrict__ Outb)
{
    int wid = threadIdx.x >> 6, lane = threadIdx.x & 63;
    int idx = blockIdx.x * 4 + wid;   // idx = k*NN + i
    int k = idx >> 12, i = idx & (NN - 1);
    int cnt = ecnt[idx];
    float di = dinv[idx];
    const unsigned* Zk = Zs + (size_t)k * NN * 64;
    int myj = edges[(size_t)idx * CAP + lane];   // coalesced 128B preload
    float ax = 0.f, ay = 0.f;
    for (int e = 0; e < cnt; e += 4) {           // all control wave-uniform
        int rem = cnt - e;
        int j0 = __shfl(myj, e);
        int j1 = __shfl(myj, e + 1);
        int j2 = __shfl(myj, e + 2);
        int j3 = __shfl(myj, e + 3);
        unsigned z0 = Zk[(size_t)j0 * 64 + lane];
        unsigned z1 = (rem > 1) ? Zk[(size_t)j1 * 64 + lane] : 0u;
        unsigned z2 = (rem > 2) ? Zk[(size_t)j2 * 64 + lane] : 0u;
        unsigned z3 = (rem > 3) ? Zk[(size_t)j3 * 64 + lane] : 0u;
        ax += (b2f((unsigned short)z0) + b2f((unsigned short)z1))
            + (b2f((unsigned short)z2) + b2f((unsigned short)z3));
        ay += (b2f((unsigned short)(z0 >> 16)) + b2f((unsigned short)(z1 >> 16)))
            + (b2f((unsigned short)(z2 >> 16)) + b2f((unsigned short)(z3 >> 16)));
    }
    unsigned zi = Zk[(size_t)i * 64 + lane];     // self term (pre-scaled = di*z_i)
    ax += b2f((unsigned short)zi);
    ay += b2f((unsigned short)(zi >> 16));
    float2 bv = *(const float2*)(bias + k * HD + 2 * lane);
    float ox = fmaf(di, ax, bv.x);
    float oy = fmaf(di, ay, bv.y);
    Outb[(size_t)idx * 64 + lane] = (unsigned)f2b(ox) | ((unsigned)f2b(oy) << 16);
}

// ======== fused biLSTM (unchanged from round 4) ====
__global__ __launch_bounds__(256) void lstm_fused(
    const unsigned short* __restrict__ G2b, unsigned short* __restrict__ hsb,
    const unsigned short* __restrict__ Wp, const float* __restrict__ bp)
{
    __shared__ unsigned short Bbuf[512 * 40];   // 40 KB
    __shared__ unsigned short Abuf[64 * 40];    // 5 KB
    __shared__ unsigned short hlds[64 * 136];   // 17 KB
    int m0 = blockIdx.x * 64;
    int dir = blockIdx.y;
    int wid = threadIdx.x >> 6, lane = threadIdx.x & 63;
    int la = lane & 15, lj = lane >> 4, kb = lj * 8;
    const unsigned short* B = Wp + (size_t)dir * 512 * 256;
    float c_st[4][2][4] = {};
    float bias[2][4];
#pragma unroll
    for (int ch = 0; ch < 2; ++ch)
#pragma unroll
        for (int g = 0; g < 4; ++g)
            bias[ch][g] = bp[dir * 512 + wid * 128 + (ch * 4 + g) * 16 + la];

    for (int t = 0; t < KG; ++t) {
        int kin = dir ? (KG - 1 - t) : t;
        f32x4 acc[4][8] = {};
        int nch = (t == 0) ? 4 : 8;
        for (int ch = 0; ch < nch; ++ch) {
            if (ch < 4) {
                int r = threadIdx.x >> 2, q = threadIdx.x & 3;
                *(uint4*)&Abuf[r * 40 + q * 8] =
                    *(const uint4*)&G2b[((size_t)kin * NN + m0 + r) * HD + ch * 32 + q * 8];
            }
#pragma unroll
            for (int it = 0; it < 8; ++it) {
                int f = threadIdx.x + it * 256;
                int r = f >> 2, q = f & 3;
                *(uint4*)&Bbuf[r * 40 + q * 8] =
                    *(const uint4*)&B[(size_t)r * 256 + ch * 32 + q * 8];
            }
            __syncthreads();
            bf16x8 bfr[8];
#pragma unroll
            for (int fi = 0; fi < 8; ++fi)
                bfr[fi] = *(const bf16x8*)&Bbuf[(wid * 128 + fi * 16 + la) * 40 + kb];
#pragma unroll
            for (int m = 0; m < 4; ++m) {
                bf16x8 afr = (ch < 4)
                    ? *(const bf16x8*)&Abuf[(m * 16 + la) * 40 + kb]
                    : *(const bf16x8*)&hlds[(m * 16 + la) * 136 + (ch - 4) * 32 + kb];
#pragma unroll
                for (int fi = 0; fi < 8; ++fi)
                    acc[m][fi] = __builtin_amdgcn_mfma_f32_16x16x32_bf16(afr, bfr[fi], acc[m][fi], 0, 0, 0);
            }
            __syncthreads();
        }
        unsigned short* hout = hsb + ((size_t)(dir * KG + kin) * NN) * HD;
#pragma unroll
        for (int m = 0; m < 4; ++m)
#pragma unroll
            for (int j = 0; j < 4; ++j) {
                int r = m * 16 + lj * 4 + j;
#pragma unroll
                for (int chf = 0; chf < 2; ++chf) {
                    int h = wid * 32 + chf * 16 + la;
                    float gi = acc[m][chf * 4 + 0][j] + bias[chf][0];
                    float gf = acc[m][chf * 4 + 1][j] + bias[chf][1];
                    float gg = acc[m][chf * 4 + 2][j] + bias[chf][2];
                    float go = acc[m][chf * 4 + 3][j] + bias[chf][3];
                    float cold = c_st[m][chf][j];
                    float si = 1.f / (1.f + __expf(-gi));
                    float sf = 1.f / (1.f + __expf(-gf));
                    float so = 1.f / (1.f + __expf(-go));
                    float e2g = __expf(2.f * gg);
                    float tg = 1.f - 2.f / (e2g + 1.f);
                    float cn = fmaf(sf, cold, si * tg);
                    float e2c = __expf(2.f * cn);
                    float tc = 1.f - 2.f / (e2c + 1.f);
                    c_st[m][chf][j] = cn;
                    unsigned short hb = f2b(so * tc);
                    hlds[r * 136 + h] = hb;
                    hout[(size_t)(m0 + r) * HD + h] = hb;
                }
            }
        __syncthreads();
    }
}

// ======== finalize: attn softmax over k -> pool (bf16 gnn) -> classify ========
__global__ __launch_bounds__(256) void finalize_kernel(
    const unsigned* __restrict__ gnnb, const unsigned* __restrict__ hsu,
    const float* __restrict__ rw, const float* __restrict__ ow,
    const float* __restrict__ ob, float* __restrict__ out)
{
    int wid = threadIdx.x >> 6, lane = threadIdx.x & 63;
    int n = blockIdx.x * 4 + wid;
    int u0 = 2 * lane;
    float w0 = rw[u0], w1 = rw[u0 + 1];
    float w2 = rw[HD + u0], w3 = rw[HD + u0 + 1];
    float lg[KG];
#pragma unroll
    for (int k = 0; k < KG; ++k) {
        unsigned hf = hsu[((size_t)k * NN + n) * 64 + lane];
        unsigned hb = hsu[((size_t)(KG + k) * NN + n) * 64 + lane];
        lg[k] = b2f((unsigned short)hf) * w0 + b2f((unsigned short)(hf >> 16)) * w1
              + b2f((unsigned short)hb) * w2 + b2f((unsigned short)(hb >> 16)) * w3;
    }
#pragma unroll
    for (int s = 32; s > 0; s >>= 1)
#pragma unroll
        for (int k = 0; k < KG; ++k) lg[k] += __shfl_xor(lg[k], s);
    float mx = lg[0];
#pragma unroll
    for (int k = 1; k < KG; ++k) mx = fmaxf(mx, lg[k]);
    float es[KG], se = 0.f;
#pragma unroll
    for (int k = 0; k < KG; ++k) { es[k] = __expf(lg[k] - mx); se += es[k]; }
    float inv = 1.f / se;
    float p0 = 0.f, p1 = 0.f;
#pragma unroll
    for (int k = 0; k < KG; ++k) {
        float a = es[k] * inv;
        unsigned g = gnnb[((size_t)k * NN + n) * 64 + lane];
        p0 = fmaf(a, b2f((unsigned short)g), p0);
        p1 = fmaf(a, b2f((unsigned short)(g >> 16)), p1);
    }
    float oc[NC];
#pragma unroll
    for (int c = 0; c < NC; ++c)
        oc[c] = p0 * ow[c * HD + u0] + p1 * ow[c * HD + u0 + 1];
#pragma unroll
    for (int s = 32; s > 0; s >>= 1)
#pragma unroll
        for (int c = 0; c < NC; ++c) oc[c] += __shfl_xor(oc[c], s);
    float omx = oc[0] + ob[0];
#pragma unroll
    for (int c = 0; c < NC; ++c) { oc[c] += ob[c]; omx = fmaxf(omx, oc[c]); }
    float osum = 0.f;
#pragma unroll
    for (int c = 0; c < NC; ++c) { oc[c] = __expf(oc[c] - omx); osum += oc[c]; }
    float oinv = 1.f / osum;
    if (lane < NC) out[(size_t)n * NC + lane] = oc[lane] * oinv;
}

extern "C" void kernel_launch(void* const* d_in, const int* in_sizes, int n_in,
                              void* d_out, int out_size, void* d_ws, size_t ws_size,
                              hipStream_t stream)
{
    const float* feat  = (const float*)d_in[0];
    const float* adj   = (const float*)d_in[1];
    const float* gw1   = (const float*)d_in[2];
    const float* gb1   = (const float*)d_in[3];
    const float* gw2   = (const float*)d_in[4];
    const float* gb2   = (const float*)d_in[5];
    const float* wih_f = (const float*)d_in[6];
    const float* whh_f = (const float*)d_in[7];
    const float* bih_f = (const float*)d_in[8];
    const float* bhh_f = (const float*)d_in[9];
    const float* wih_b = (const float*)d_in[10];
    const float* whh_b = (const float*)d_in[11];
    const float* bih_b = (const float*)d_in[12];
    const float* bhh_b = (const float*)d_in[13];
    const float* rw    = (const float*)d_in[14];
    const float* ow    = (const float*)d_in[16];
    const float* ob    = (const float*)d_in[17];
    float* out = (float*)d_out;

    char* ws = (char*)d_ws;
    float*          dinv  = (float*)(ws);                      // 64 KB
    int*            ecnt  = (int*)(ws + 65536);                // 64 KB
    unsigned short* edges = (unsigned short*)(ws + 131072);    // 2 MB   -> 2228224
    unsigned*       featb = (unsigned*)(ws + 2228224);         // 1 MB   -> 3276800
    unsigned short* Zs    = (unsigned short*)(ws + 3276800);   // 4 MB   -> 7471104
    unsigned*       G1b   = (unsigned*)(ws + 7471104);         // 4 MB   -> 11665408
    unsigned*       G2b   = (unsigned*)(ws + 11665408);        // 4 MB   -> 15859712
    unsigned short* hsb   = (unsigned short*)(ws + 15859712);  // 8 MB   -> 24248320
    unsigned short* Wp    = (unsigned short*)(ws + 24248320);  // 512 KB -> 24772608
    float*          bp    = (float*)(ws + 24772608);           // 4 KB   -> 24776704
    unsigned short* Wg1p  = (unsigned short*)(ws + 24776704);  // 128 KB -> 24907776
    unsigned short* Wg2p  = (unsigned short*)(ws + 24907776);  // 128 KB

    setup_kernel<<<NN + 2564, 256, 0, stream>>>(
        adj, feat, wih_f, whh_f, bih_f, bhh_f, wih_b, whh_b, bih_b, bhh_b,
        gw1, gw2, dinv, ecnt, edges, featb, Wp, bp, Wg1p, Wg2p);
    gemm_gcn_mfma<<<dim3(KG, 64), 256, 0, stream>>>(
        (const unsigned short*)featb, 0, Wg1p, dinv, Zs);
    spmm_kernel<<<KG * NN / 4, 256, 0, stream>>>(
        (const unsigned*)Zs, dinv, ecnt, edges, gb1, G1b);
    gemm_gcn_mfma<<<dim3(KG, 64), 256, 0, stream>>>(
        (const unsigned short*)G1b, 1, Wg2p, dinv, Zs);
    spmm_kernel<<<KG * NN / 4, 256, 0, stream>>>(
        (const unsigned*)Zs, dinv, ecnt, edges, gb2, G2b);
    lstm_fused<<<dim3(64, 2), 256, 0, stream>>>(
        (const unsigned short*)G2b, hsb, Wp, bp);
    finalize_kernel<<<NN / 4, 256, 0, stream>>>(
        G2b, (const unsigned*)hsb, rw, ow, ob, out);
}